// Round 1
// baseline (621.594 us; speedup 1.0000x reference)
//
#include <hip/hip_runtime.h>
#include <math.h>

#define GROUPS 2
#define NVARS  320
#define VDIM   128
#define NCOLS  640      // GROUPS*NVARS
#define FSZ    768
#define BT     32768    // 16*2048
#define QDIM   256      // GROUPS*VDIM

// ---------------- Phase A: logits = x @ W + b (fp32, vector ALU) ----------------
#define BM 64
#define BN 64
#define BK 16

__global__ __launch_bounds__(256) void gemm_f32(
    const float* __restrict__ x, const float* __restrict__ W,
    const float* __restrict__ bias, float* __restrict__ logits, int row0)
{
    __shared__ float As[BK][BM + 4];   // [k][m], +4 keeps 16B alignment & rotates banks
    __shared__ float Bs[BK][BN];       // [k][n]
    const int tid = threadIdx.x;
    const int tx = tid & 15;           // col quad  (4 cols)
    const int ty = tid >> 4;           // row quad  (4 rows)
    const int m0 = blockIdx.y * BM;    // chunk-local row base
    const int n0 = blockIdx.x * BN;

    const int arow = tid >> 2;         // 0..63
    const int akq  = (tid & 3) << 2;   // 0,4,8,12
    const int brow = tid >> 4;         // 0..15
    const int bcol = (tid & 15) << 2;  // 0..60

    const float* xg = x + (size_t)(row0 + m0 + arow) * FSZ + akq;
    const float* wg = W + (size_t)brow * NCOLS + n0 + bcol;

    float4 ra = *(const float4*)xg;          // prefetch k-tile 0
    float4 rb = *(const float4*)wg;

    float acc[4][4];
    #pragma unroll
    for (int i = 0; i < 4; ++i)
        #pragma unroll
        for (int j = 0; j < 4; ++j) acc[i][j] = 0.f;

    for (int kt = 0; kt < FSZ; kt += BK) {
        __syncthreads();                      // previous tile's compute done
        As[akq+0][arow] = ra.x;
        As[akq+1][arow] = ra.y;
        As[akq+2][arow] = ra.z;
        As[akq+3][arow] = ra.w;
        *(float4*)&Bs[brow][bcol] = rb;
        __syncthreads();
        if (kt + BK < FSZ) {                  // issue next tile's loads over compute
            ra = *(const float4*)(xg + kt + BK);
            rb = *(const float4*)(wg + (size_t)(kt + BK) * NCOLS);
        }
        #pragma unroll
        for (int k = 0; k < BK; ++k) {
            float4 a4 = *(const float4*)&As[k][ty << 2];
            float4 b4 = *(const float4*)&Bs[k][tx << 2];
            const float av[4] = {a4.x, a4.y, a4.z, a4.w};
            const float bv[4] = {b4.x, b4.y, b4.z, b4.w};
            #pragma unroll
            for (int i = 0; i < 4; ++i)
                #pragma unroll
                for (int j = 0; j < 4; ++j)
                    acc[i][j] = fmaf(av[i], bv[j], acc[i][j]);
        }
    }

    const float4 bb = *(const float4*)&bias[n0 + (tx << 2)];
    const float bvv[4] = {bb.x, bb.y, bb.z, bb.w};
    #pragma unroll
    for (int i = 0; i < 4; ++i) {
        float4 o;
        o.x = acc[i][0] + bvv[0];
        o.y = acc[i][1] + bvv[1];
        o.z = acc[i][2] + bvv[2];
        o.w = acc[i][3] + bvv[3];
        *(float4*)&logits[(size_t)(m0 + (ty << 2) + i) * NCOLS + n0 + (tx << 2)] = o;
    }
}

// ---------------- Phase B: per-row argmax + softmax accumulate + codebook gather ----------------
#define RPB 16   // rows per block (4 waves x 4 rows)

__global__ __launch_bounds__(256) void rows_kernel(
    const float* __restrict__ logits, const float* __restrict__ cb,
    float* __restrict__ qout, float* __restrict__ avg, int row0)
{
    __shared__ float probacc[4][NCOLS];   // per-wave private accumulator (no atomics)
    const int tid  = threadIdx.x;
    const int wid  = tid >> 6;
    const int lane = tid & 63;

    for (int c = tid; c < 4 * NCOLS; c += 256) ((float*)probacc)[c] = 0.f;
    __syncthreads();

    #pragma unroll
    for (int i = 0; i < RPB / 4; ++i) {
        const int rl = blockIdx.x * RPB + wid * (RPB / 4) + i;  // chunk-local row
        const float* lr = logits + (size_t)rl * NCOLS;
        const size_t grow = (size_t)row0 + rl;
        #pragma unroll
        for (int g = 0; g < GROUPS; ++g) {
            float v[5];
            #pragma unroll
            for (int j = 0; j < 5; ++j) v[j] = lr[g * NVARS + lane + 64 * j];
            // in-lane argmax (lowest index wins ties)
            float m = v[0]; int idx = lane;
            #pragma unroll
            for (int j = 1; j < 5; ++j)
                if (v[j] > m) { m = v[j]; idx = lane + 64 * j; }
            // cross-lane argmax over all 64 lanes
            #pragma unroll
            for (int off = 32; off > 0; off >>= 1) {
                float om = __shfl_xor(m, off);
                int   oi = __shfl_xor(idx, off);
                if (om > m || (om == m && oi < idx)) { m = om; idx = oi; }
            }
            // softmax sum
            float e[5]; float s = 0.f;
            #pragma unroll
            for (int j = 0; j < 5; ++j) { e[j] = expf(v[j] - m); s += e[j]; }
            #pragma unroll
            for (int off = 32; off > 0; off >>= 1) s += __shfl_xor(s, off);
            const float inv = 1.0f / s;
            #pragma unroll
            for (int j = 0; j < 5; ++j)
                probacc[wid][g * NVARS + lane + 64 * j] += e[j] * inv;
            // q gather: copy codebook row (128 floats = 2 per lane)
            const float2* src = (const float2*)(cb + (size_t)(g * NVARS + idx) * VDIM);
            float2* dst = (float2*)(qout + grow * QDIM + (size_t)g * VDIM);
            dst[lane] = src[lane];
        }
    }
    __syncthreads();
    for (int c = tid; c < NCOLS; c += 256) {
        float s = probacc[0][c] + probacc[1][c] + probacc[2][c] + probacc[3][c];
        atomicAdd(&avg[c], s);
    }
}

// ---------------- Phase C: perplexity finalize + temp ----------------
__global__ __launch_bounds__(64) void finalize_kernel(
    const float* __restrict__ avg, float* __restrict__ out)
{
    const int lane = threadIdx.x;
    float pp[GROUPS];
    #pragma unroll
    for (int g = 0; g < GROUPS; ++g) {
        float s = 0.f;
        #pragma unroll
        for (int j = 0; j < 5; ++j) {
            float p = avg[g * NVARS + lane + 64 * j] * (1.0f / (float)BT);
            s += p * logf(p + 1e-7f);
        }
        #pragma unroll
        for (int off = 32; off > 0; off >>= 1) s += __shfl_xor(s, off);
        pp[g] = expf(-s);
    }
    if (lane == 0) {
        float ppl = pp[0] + pp[1];
        out[(size_t)BT * QDIM]     = ((float)NCOLS - ppl) / (float)NCOLS;
        out[(size_t)BT * QDIM + 1] = 2.0f;
    }
}

// ---------------- launcher ----------------
extern "C" void kernel_launch(void* const* d_in, const int* in_sizes, int n_in,
                              void* d_out, int out_size, void* d_ws, size_t ws_size,
                              hipStream_t stream)
{
    const float* x  = (const float*)d_in[0];
    const float* W  = (const float*)d_in[1];
    const float* b  = (const float*)d_in[2];
    const float* cb = (const float*)d_in[3];
    float* out = (float*)d_out;

    float* avg    = (float*)d_ws;                       // 640 floats
    float* logits = (float*)((char*)d_ws + 4096);       // chunked logits buffer

    // ws-adaptive chunking: each chunk needs nr*640*4 bytes of logits scratch
    long long avail = (long long)ws_size - 4096;
    long long mr = avail / (NCOLS * 4);
    int max_rows = (int)((mr / 64) * 64);
    if (max_rows < 64) max_rows = 64;
    if (max_rows > BT) max_rows = BT;

    hipMemsetAsync(avg, 0, NCOLS * sizeof(float), stream);
    for (int r0 = 0; r0 < BT; r0 += max_rows) {
        int nr = BT - r0; if (nr > max_rows) nr = max_rows;
        dim3 gA(NCOLS / BN, nr / BM);
        gemm_f32<<<gA, 256, 0, stream>>>(x, W, b, logits, r0);
        rows_kernel<<<nr / RPB, 256, 0, stream>>>(logits, cb, out, avg, r0);
    }
    finalize_kernel<<<1, 64, 0, stream>>>(avg, out);
}

// Round 2
// 432.822 us; speedup vs baseline: 1.4361x; 1.4361x over previous
//
#include <hip/hip_runtime.h>
#include <math.h>

#define GROUPS 2
#define NVARS  320
#define VDIM   128
#define NCOLS  640
#define FSZ    768
#define BTOT   32768
#define QDIM   256
#define KT     24        // 768/32 k-tiles
#define GAPTH  0.05f
#define LISTCAP 131072

typedef __bf16 bf16x8 __attribute__((ext_vector_type(8)));
typedef float  f32x4  __attribute__((ext_vector_type(4)));

// ---------------- helpers ----------------
__device__ __forceinline__ void gl_lds16(const void* g, void* l) {
    __builtin_amdgcn_global_load_lds(
        (const __attribute__((address_space(1))) unsigned int*)g,
        (__attribute__((address_space(3))) unsigned int*)l, 16, 0, 0);
}

// ---------------- x pre-pass: f32 -> tile-linear bf16 hi/lo ----------------
// layout: tile (mblk,kblk) = 4096 bf16, unit u = kq*128 + m holds
// x[row0+mblk*128+m][kblk*32 + kq*8 .. +8]
__global__ __launch_bounds__(128) void xpre(
    const float* __restrict__ x, __bf16* __restrict__ xh, __bf16* __restrict__ xl, int row0)
{
    const int b = blockIdx.x;
    const int mblk = b / KT, kblk = b % KT;
    const int m = threadIdx.x;
    const float* src = x + (size_t)(row0 + mblk*128 + m) * FSZ + kblk*32;
    const size_t tbase = ((size_t)mblk*KT + kblk) * 4096;
    #pragma unroll
    for (int kq = 0; kq < 4; ++kq) {
        float4 a = ((const float4*)src)[kq*2];
        float4 c = ((const float4*)src)[kq*2+1];
        float vv[8] = {a.x,a.y,a.z,a.w,c.x,c.y,c.z,c.w};
        bf16x8 h, l;
        #pragma unroll
        for (int j = 0; j < 8; ++j) {
            __bf16 hh = (__bf16)vv[j];
            h[j] = hh;
            l[j] = (__bf16)(vv[j] - (float)hh);
        }
        ((bf16x8*)(xh + tbase))[kq*128 + m] = h;
        ((bf16x8*)(xl + tbase))[kq*128 + m] = l;
    }
}

// ---------------- W pre-pass (runs once; W is 2MB) ----------------
// tile (nblk,kblk): unit u = kq*128 + n holds W[kblk*32+kq*8+j][nblk*128+n]
__global__ __launch_bounds__(128) void wpre(
    const float* __restrict__ W, __bf16* __restrict__ wh, __bf16* __restrict__ wl)
{
    const int b = blockIdx.x;
    const int nblk = b / KT, kblk = b % KT;
    const int n = threadIdx.x;
    const size_t tbase = ((size_t)nblk*KT + kblk) * 4096;
    #pragma unroll
    for (int kq = 0; kq < 4; ++kq) {
        bf16x8 h, l;
        #pragma unroll
        for (int j = 0; j < 8; ++j) {
            float v = W[(size_t)(kblk*32 + kq*8 + j) * NCOLS + nblk*128 + n];
            __bf16 hh = (__bf16)v;
            h[j] = hh;
            l[j] = (__bf16)(v - (float)hh);
        }
        ((bf16x8*)(wh + tbase))[kq*128 + n] = h;
        ((bf16x8*)(wl + tbase))[kq*128 + n] = l;
    }
}

// ---------------- MFMA GEMM: logits = x@W + b via bf16x3 ----------------
__global__ __launch_bounds__(256) void gemm_mfma(
    const __bf16* __restrict__ xh, const __bf16* __restrict__ xl,
    const __bf16* __restrict__ wh, const __bf16* __restrict__ wl,
    const float* __restrict__ bias, float* __restrict__ logits, int nwg)
{
    __shared__ __bf16 lds[16384];   // AH | AL | BH | BL, 4096 bf16 each (32 KB)

    // bijective XCD swizzle (m204), n-fastest so same-m blocks share an XCD L2
    const int b = blockIdx.x;
    const int q8 = nwg >> 3, r8 = nwg & 7;
    const int xcd = b & 7, pos = b >> 3;
    const int L = (xcd < r8 ? xcd*(q8+1) : r8*(q8+1) + (xcd - r8)*q8) + pos;
    const int mblk = L / 5, nblk = L % 5;

    const int tid = threadIdx.x;
    const int w = tid >> 6, lane = tid & 63;
    const int wr = w >> 1, wc = w & 1;
    const int qq = lane >> 4, rr = lane & 15;

    f32x4 acc[4][4];
    #pragma unroll
    for (int i = 0; i < 4; ++i)
        #pragma unroll
        for (int j = 0; j < 4; ++j) acc[i][j] = (f32x4)0.f;

    const int ab = qq*128 + wr*64 + rr;   // 16B-unit index for A frags
    const int bb = qq*128 + wc*64 + rr;   // for B frags

    for (int kt = 0; kt < KT; ++kt) {
        __syncthreads();                                   // LDS free to overwrite
        const __bf16* ah_s = xh + ((size_t)mblk*KT + kt)*4096;
        const __bf16* al_s = xl + ((size_t)mblk*KT + kt)*4096;
        const __bf16* bh_s = wh + ((size_t)nblk*KT + kt)*4096;
        const __bf16* bl_s = wl + ((size_t)nblk*KT + kt)*4096;
        #pragma unroll
        for (int i = 0; i < 2; ++i) {
            const int u  = w*128 + i*64;       // wave-uniform unit base
            const int el = (u + lane)*8;       // per-lane global elem
            const int ed = u*8;                // uniform LDS elem
            gl_lds16(ah_s + el, &lds[0     + ed]);
            gl_lds16(al_s + el, &lds[4096  + ed]);
            gl_lds16(bh_s + el, &lds[8192  + ed]);
            gl_lds16(bl_s + el, &lds[12288 + ed]);
        }
        __syncthreads();                                   // staged data ready

        const bf16x8* LAH = (const bf16x8*)&lds[0];
        const bf16x8* LAL = (const bf16x8*)&lds[4096];
        const bf16x8* LBH = (const bf16x8*)&lds[8192];
        const bf16x8* LBL = (const bf16x8*)&lds[12288];
        bf16x8 ah[4], al[4], bh[4], bl[4];
        #pragma unroll
        for (int mf = 0; mf < 4; ++mf) { ah[mf] = LAH[ab + mf*16]; al[mf] = LAL[ab + mf*16]; }
        #pragma unroll
        for (int nf = 0; nf < 4; ++nf) { bh[nf] = LBH[bb + nf*16]; bl[nf] = LBL[bb + nf*16]; }

        #pragma unroll
        for (int mf = 0; mf < 4; ++mf)
            #pragma unroll
            for (int nf = 0; nf < 4; ++nf) {
                acc[mf][nf] = __builtin_amdgcn_mfma_f32_16x16x32_bf16(ah[mf], bh[nf], acc[mf][nf], 0, 0, 0);
                acc[mf][nf] = __builtin_amdgcn_mfma_f32_16x16x32_bf16(al[mf], bh[nf], acc[mf][nf], 0, 0, 0);
                acc[mf][nf] = __builtin_amdgcn_mfma_f32_16x16x32_bf16(ah[mf], bl[nf], acc[mf][nf], 0, 0, 0);
            }
    }

    // epilogue: C/D layout col=lane&15, row=(lane>>4)*4+j  [verified m89/m91]
    const int row0b = mblk*128 + wr*64;
    const int col0  = nblk*128 + wc*64;
    #pragma unroll
    for (int nf = 0; nf < 4; ++nf) {
        const int col = col0 + nf*16 + rr;
        const float bv = bias[col];
        #pragma unroll
        for (int mf = 0; mf < 4; ++mf) {
            const int rowb = row0b + mf*16 + qq*4;
            #pragma unroll
            for (int j = 0; j < 4; ++j)
                logits[(size_t)(rowb + j)*NCOLS + col] = acc[mf][nf][j] + bv;
        }
    }
}

// ---------------- rows: argmax + gap-flag + softmax partials + gather ----------------
#define RPB 16
__global__ __launch_bounds__(256) void rows_kernel(
    const float* __restrict__ logits, const float* __restrict__ cb,
    float* __restrict__ qout, float* __restrict__ partials,
    int* __restrict__ counter, int* __restrict__ list, int row0)
{
    __shared__ float probacc[4][NCOLS];
    const int tid = threadIdx.x, wid = tid >> 6, lane = tid & 63;
    for (int c = tid; c < 4*NCOLS; c += 256) ((float*)probacc)[c] = 0.f;
    __syncthreads();

    #pragma unroll
    for (int i = 0; i < RPB/4; ++i) {
        const int rl = blockIdx.x*RPB + wid*(RPB/4) + i;
        const float* lr = logits + (size_t)rl*NCOLS;
        const size_t grow = (size_t)row0 + rl;
        #pragma unroll
        for (int g = 0; g < GROUPS; ++g) {
            float v[5];
            #pragma unroll
            for (int j = 0; j < 5; ++j) v[j] = lr[g*NVARS + lane + 64*j];
            // in-lane top-2 with lowest-index tie-break
            float m = v[0], m2 = -3.4e38f; int idx = lane;
            #pragma unroll
            for (int j = 1; j < 5; ++j) {
                if (v[j] > m) { m2 = m; m = v[j]; idx = lane + 64*j; }
                else m2 = fmaxf(m2, v[j]);
            }
            // cross-lane top-2 + argmax
            #pragma unroll
            for (int off = 32; off > 0; off >>= 1) {
                float om  = __shfl_xor(m, off);
                int   oi  = __shfl_xor(idx, off);
                float om2 = __shfl_xor(m2, off);
                if (om > m || (om == m && oi < idx)) { m2 = fmaxf(m, om2); m = om; idx = oi; }
                else m2 = fmaxf(m2, om);
            }
            // softmax accumulate
            float e[5], s = 0.f;
            #pragma unroll
            for (int j = 0; j < 5; ++j) { e[j] = expf(v[j] - m); s += e[j]; }
            #pragma unroll
            for (int off = 32; off > 0; off >>= 1) s += __shfl_xor(s, off);
            const float inv = 1.0f / s;
            #pragma unroll
            for (int j = 0; j < 5; ++j)
                probacc[wid][g*NVARS + lane + 64*j] += e[j] * inv;
            // near-tie -> fixup list
            if (lane == 0 && (m - m2) < GAPTH) {
                int p = atomicAdd(counter, 1);
                if (p < LISTCAP) list[p] = ((int)grow << 1) | g;
            }
            // codebook gather
            const float2* srcc = (const float2*)(cb + (size_t)(g*NVARS + idx)*VDIM);
            float2* dst = (float2*)(qout + grow*QDIM + (size_t)g*VDIM);
            dst[lane] = srcc[lane];
        }
    }
    __syncthreads();
    const size_t pb = (size_t)(row0 >> 4) + blockIdx.x;
    for (int c = tid; c < NCOLS; c += 256)
        partials[pb*NCOLS + c] = probacc[0][c] + probacc[1][c] + probacc[2][c] + probacc[3][c];
}

// ---------------- fixup: exact fp32 recompute of near-tie row-groups ----------------
__global__ __launch_bounds__(64) void fixup_kernel(
    const float* __restrict__ x, const float* __restrict__ W,
    const float* __restrict__ bias, const float* __restrict__ cb,
    float* __restrict__ qout, const int* __restrict__ counter, const int* __restrict__ list)
{
    int cnt = *counter; if (cnt > LISTCAP) cnt = LISTCAP;
    const int lane = threadIdx.x;
    for (int e = blockIdx.x; e < cnt; e += gridDim.x) {
        const int ent = list[e];
        const int row = ent >> 1, g = ent & 1;
        const float* xr = x + (size_t)row*FSZ;
        float acc[5];
        #pragma unroll
        for (int j = 0; j < 5; ++j) acc[j] = bias[g*NVARS + lane + 64*j];
        for (int k = 0; k < FSZ; ++k) {
            const float xv = xr[k];
            const float* wrow = W + (size_t)k*NCOLS + g*NVARS;
            #pragma unroll
            for (int j = 0; j < 5; ++j) acc[j] = fmaf(xv, wrow[lane + 64*j], acc[j]);
        }
        float m = acc[0]; int idx = lane;
        #pragma unroll
        for (int j = 1; j < 5; ++j) if (acc[j] > m) { m = acc[j]; idx = lane + 64*j; }
        #pragma unroll
        for (int off = 32; off > 0; off >>= 1) {
            float om = __shfl_xor(m, off);
            int   oi = __shfl_xor(idx, off);
            if (om > m || (om == m && oi < idx)) { m = om; idx = oi; }
        }
        const float2* srcc = (const float2*)(cb + (size_t)(g*NVARS + idx)*VDIM);
        float2* dst = (float2*)(qout + (size_t)row*QDIM + (size_t)g*VDIM);
        dst[lane] = srcc[lane];
    }
}

// ---------------- reduce partials -> avg ----------------
__global__ __launch_bounds__(64) void reduce_kernel(
    const float* __restrict__ partials, float* __restrict__ avg)
{
    const int c = blockIdx.x, lane = threadIdx.x;
    float s = 0.f;
    for (int p = lane; p < BTOT/RPB; p += 64) s += partials[(size_t)p*NCOLS + c];
    #pragma unroll
    for (int off = 32; off > 0; off >>= 1) s += __shfl_xor(s, off);
    if (lane == 0) avg[c] = s;
}

// ---------------- finalize: ppl + temp ----------------
__global__ __launch_bounds__(64) void finalize_kernel(
    const float* __restrict__ avg, float* __restrict__ out)
{
    const int lane = threadIdx.x;
    float pp[GROUPS];
    #pragma unroll
    for (int g = 0; g < GROUPS; ++g) {
        float s = 0.f;
        #pragma unroll
        for (int j = 0; j < 5; ++j) {
            float p = avg[g*NVARS + lane + 64*j] * (1.0f/(float)BTOT);
            s += p * logf(p + 1e-7f);
        }
        #pragma unroll
        for (int off = 32; off > 0; off >>= 1) s += __shfl_xor(s, off);
        pp[g] = expf(-s);
    }
    if (lane == 0) {
        float ppl = pp[0] + pp[1];
        out[(size_t)BTOT*QDIM]     = ((float)NCOLS - ppl) / (float)NCOLS;
        out[(size_t)BTOT*QDIM + 1] = 2.0f;
    }
}

// ---------------- launcher ----------------
extern "C" void kernel_launch(void* const* d_in, const int* in_sizes, int n_in,
                              void* d_out, int out_size, void* d_ws, size_t ws_size,
                              hipStream_t stream)
{
    const float* x  = (const float*)d_in[0];
    const float* W  = (const float*)d_in[1];
    const float* b  = (const float*)d_in[2];
    const float* cb = (const float*)d_in[3];
    float* out = (float*)d_out;

    char* ws = (char*)d_ws;
    int*   counter  = (int*)ws;                               // 4 B
    float* avg      = (float*)(ws + 1024);                    // 2560 B
    int*   list     = (int*)(ws + 8192);                      // 512 KB
    float* partials = (float*)(ws + 532480);                  // 2048*640*4 = 5 MB
    __bf16* wh      = (__bf16*)(ws + 5775360);                // 960 KB
    __bf16* wl      = (__bf16*)(ws + 6758400);                // 960 KB
    char* chunkbase = ws + 7741440;

    // ws-adaptive row chunking: per-row cost = 768*2*2 (xh+xl) + 640*4 (logits) = 5632 B
    long long avail = (long long)ws_size - 7741440;
    long long rmax = avail / 5632;
    int R = (int)((rmax / 1024) * 1024);
    if (R < 1024) R = (int)((rmax / 128) * 128);
    if (R > BTOT) R = BTOT;
    if (R < 128) R = 128;   // should not happen given round-1 ws evidence

    hipMemsetAsync(counter, 0, 4, stream);
    wpre<<<5*KT, 128, 0, stream>>>(W, wh, wl);

    for (int row0 = 0; row0 < BTOT; row0 += R) {
        int Rc = BTOT - row0; if (Rc > R) Rc = R;
        const int nmb = Rc / 128;
        __bf16* xh = (__bf16*)chunkbase;
        __bf16* xl = xh + (size_t)nmb*KT*4096;
        float* logits = (float*)(xl + (size_t)nmb*KT*4096);

        xpre<<<nmb*KT, 128, 0, stream>>>(x, xh, xl, row0);
        const int nwg = nmb * 5;
        gemm_mfma<<<nwg, 256, 0, stream>>>(xh, xl, wh, wl, b, logits, nwg);
        rows_kernel<<<Rc/RPB, 256, 0, stream>>>(logits, cb, out, partials, counter, list, row0);
    }
    fixup_kernel<<<512, 64, 0, stream>>>(x, W, b, cb, out, counter, list);
    reduce_kernel<<<NCOLS, 64, 0, stream>>>(partials, avg);
    finalize_kernel<<<1, 64, 0, stream>>>(avg, out);
}

// Round 4
// 366.225 us; speedup vs baseline: 1.6973x; 1.1818x over previous
//
#include <hip/hip_runtime.h>
#include <math.h>

#define GROUPS 2
#define NVARS  320
#define VDIM   128
#define NCOLS  640
#define FSZ    768
#define BTOT   32768
#define QDIM   256
#define KT     24        // 768/32 k-tiles
#define GAPTH  0.05f
#define LISTCAP 131072

typedef __bf16 bf16x8 __attribute__((ext_vector_type(8)));
typedef float  f32x4  __attribute__((ext_vector_type(4)));

// ---------------- helpers ----------------
__device__ __forceinline__ void gl_lds16(const void* g, void* l) {
    __builtin_amdgcn_global_load_lds(
        (const __attribute__((address_space(1))) unsigned int*)g,
        (__attribute__((address_space(3))) unsigned int*)l, 16, 0, 0);
}

// ---------------- x pre-pass: f32 -> tile-linear bf16 hi/lo ----------------
__global__ __launch_bounds__(128) void xpre(
    const float* __restrict__ x, __bf16* __restrict__ xh, __bf16* __restrict__ xl, int row0)
{
    const int b = blockIdx.x;
    const int mblk = b / KT, kblk = b % KT;
    const int m = threadIdx.x;
    const float* src = x + (size_t)(row0 + mblk*128 + m) * FSZ + kblk*32;
    const size_t tbase = ((size_t)mblk*KT + kblk) * 4096;
    #pragma unroll
    for (int kq = 0; kq < 4; ++kq) {
        float4 a = ((const float4*)src)[kq*2];
        float4 c = ((const float4*)src)[kq*2+1];
        float vv[8] = {a.x,a.y,a.z,a.w,c.x,c.y,c.z,c.w};
        bf16x8 h, l;
        #pragma unroll
        for (int j = 0; j < 8; ++j) {
            __bf16 hh = (__bf16)vv[j];
            h[j] = hh;
            l[j] = (__bf16)(vv[j] - (float)hh);
        }
        ((bf16x8*)(xh + tbase))[kq*128 + m] = h;
        ((bf16x8*)(xl + tbase))[kq*128 + m] = l;
    }
}

// ---------------- W pre-pass (runs once; W is 2MB) ----------------
__global__ __launch_bounds__(128) void wpre(
    const float* __restrict__ W, __bf16* __restrict__ wh, __bf16* __restrict__ wl)
{
    const int b = blockIdx.x;
    const int nblk = b / KT, kblk = b % KT;
    const int n = threadIdx.x;
    const size_t tbase = ((size_t)nblk*KT + kblk) * 4096;
    #pragma unroll
    for (int kq = 0; kq < 4; ++kq) {
        bf16x8 h, l;
        #pragma unroll
        for (int j = 0; j < 8; ++j) {
            float v = W[(size_t)(kblk*32 + kq*8 + j) * NCOLS + nblk*128 + n];
            __bf16 hh = (__bf16)v;
            h[j] = hh;
            l[j] = (__bf16)(v - (float)hh);
        }
        ((bf16x8*)(wh + tbase))[kq*128 + n] = h;
        ((bf16x8*)(wl + tbase))[kq*128 + n] = l;
    }
}

// ---------------- MFMA GEMM: logits = x@W + b via bf16x3 ----------------
__global__ __launch_bounds__(256) void gemm_mfma(
    const __bf16* __restrict__ xh, const __bf16* __restrict__ xl,
    const __bf16* __restrict__ wh, const __bf16* __restrict__ wl,
    const float* __restrict__ bias, float* __restrict__ logits, int nwg)
{
    __shared__ __bf16 lds[16384];   // AH | AL | BH | BL, 4096 bf16 each (32 KB)

    const int b = blockIdx.x;
    const int q8 = nwg >> 3, r8 = nwg & 7;
    const int xcd = b & 7, pos = b >> 3;
    const int L = (xcd < r8 ? xcd*(q8+1) : r8*(q8+1) + (xcd - r8)*q8) + pos;
    const int mblk = L / 5, nblk = L % 5;

    const int tid = threadIdx.x;
    const int w = tid >> 6, lane = tid & 63;
    const int wr = w >> 1, wc = w & 1;
    const int qq = lane >> 4, rr = lane & 15;

    f32x4 acc[4][4];
    #pragma unroll
    for (int i = 0; i < 4; ++i)
        #pragma unroll
        for (int j = 0; j < 4; ++j) acc[i][j] = (f32x4)0.f;

    const int ab = qq*128 + wr*64 + rr;
    const int bb = qq*128 + wc*64 + rr;

    for (int kt = 0; kt < KT; ++kt) {
        __syncthreads();
        const __bf16* ah_s = xh + ((size_t)mblk*KT + kt)*4096;
        const __bf16* al_s = xl + ((size_t)mblk*KT + kt)*4096;
        const __bf16* bh_s = wh + ((size_t)nblk*KT + kt)*4096;
        const __bf16* bl_s = wl + ((size_t)nblk*KT + kt)*4096;
        #pragma unroll
        for (int i = 0; i < 2; ++i) {
            const int u  = w*128 + i*64;
            const int el = (u + lane)*8;
            const int ed = u*8;
            gl_lds16(ah_s + el, &lds[0     + ed]);
            gl_lds16(al_s + el, &lds[4096  + ed]);
            gl_lds16(bh_s + el, &lds[8192  + ed]);
            gl_lds16(bl_s + el, &lds[12288 + ed]);
        }
        __syncthreads();

        const bf16x8* LAH = (const bf16x8*)&lds[0];
        const bf16x8* LAL = (const bf16x8*)&lds[4096];
        const bf16x8* LBH = (const bf16x8*)&lds[8192];
        const bf16x8* LBL = (const bf16x8*)&lds[12288];
        bf16x8 ah[4], al[4], bh[4], bl[4];
        #pragma unroll
        for (int mf = 0; mf < 4; ++mf) { ah[mf] = LAH[ab + mf*16]; al[mf] = LAL[ab + mf*16]; }
        #pragma unroll
        for (int nf = 0; nf < 4; ++nf) { bh[nf] = LBH[bb + nf*16]; bl[nf] = LBL[bb + nf*16]; }

        #pragma unroll
        for (int mf = 0; mf < 4; ++mf)
            #pragma unroll
            for (int nf = 0; nf < 4; ++nf) {
                acc[mf][nf] = __builtin_amdgcn_mfma_f32_16x16x32_bf16(ah[mf], bh[nf], acc[mf][nf], 0, 0, 0);
                acc[mf][nf] = __builtin_amdgcn_mfma_f32_16x16x32_bf16(al[mf], bh[nf], acc[mf][nf], 0, 0, 0);
                acc[mf][nf] = __builtin_amdgcn_mfma_f32_16x16x32_bf16(ah[mf], bl[nf], acc[mf][nf], 0, 0, 0);
            }
    }

    const int row0b = mblk*128 + wr*64;
    const int col0  = nblk*128 + wc*64;
    #pragma unroll
    for (int nf = 0; nf < 4; ++nf) {
        const int col = col0 + nf*16 + rr;
        const float bv = bias[col];
        #pragma unroll
        for (int mf = 0; mf < 4; ++mf) {
            const int rowb = row0b + mf*16 + qq*4;
            #pragma unroll
            for (int j = 0; j < 4; ++j)
                logits[(size_t)(rowb + j)*NCOLS + col] = acc[mf][nf][j] + bv;
        }
    }
}

// ---------------- rows: argmax + gap-flag + softmax partials + gather ----------------
#define RPB 16
__global__ __launch_bounds__(256) void rows_kernel(
    const float* __restrict__ logits, const float* __restrict__ cb,
    float* __restrict__ qout, float* __restrict__ partials,
    int* __restrict__ counter, int* __restrict__ list, int row0)
{
    __shared__ float probacc[4][NCOLS];
    const int tid = threadIdx.x, wid = tid >> 6, lane = tid & 63;
    for (int c = tid; c < 4*NCOLS; c += 256) ((float*)probacc)[c] = 0.f;
    __syncthreads();

    #pragma unroll
    for (int i = 0; i < RPB/4; ++i) {
        const int rl = blockIdx.x*RPB + wid*(RPB/4) + i;
        const float* lr = logits + (size_t)rl*NCOLS;
        const size_t grow = (size_t)row0 + rl;
        #pragma unroll
        for (int g = 0; g < GROUPS; ++g) {
            float v[5];
            #pragma unroll
            for (int j = 0; j < 5; ++j) v[j] = lr[g*NVARS + lane + 64*j];
            float m = v[0], m2 = -3.4e38f; int idx = lane;
            #pragma unroll
            for (int j = 1; j < 5; ++j) {
                if (v[j] > m) { m2 = m; m = v[j]; idx = lane + 64*j; }
                else m2 = fmaxf(m2, v[j]);
            }
            #pragma unroll
            for (int off = 32; off > 0; off >>= 1) {
                float om  = __shfl_xor(m, off);
                int   oi  = __shfl_xor(idx, off);
                float om2 = __shfl_xor(m2, off);
                if (om > m || (om == m && oi < idx)) { m2 = fmaxf(m, om2); m = om; idx = oi; }
                else m2 = fmaxf(m2, om);
            }
            float e[5], s = 0.f;
            #pragma unroll
            for (int j = 0; j < 5; ++j) { e[j] = expf(v[j] - m); s += e[j]; }
            #pragma unroll
            for (int off = 32; off > 0; off >>= 1) s += __shfl_xor(s, off);
            const float inv = 1.0f / s;
            #pragma unroll
            for (int j = 0; j < 5; ++j)
                probacc[wid][g*NVARS + lane + 64*j] += e[j] * inv;
            if (lane == 0 && (m - m2) < GAPTH) {
                int p = atomicAdd(counter, 1);
                if (p < LISTCAP) list[p] = ((int)grow << 1) | g;
            }
            const float2* srcc = (const float2*)(cb + (size_t)(g*NVARS + idx)*VDIM);
            float2* dst = (float2*)(qout + grow*QDIM + (size_t)g*VDIM);
            dst[lane] = srcc[lane];
        }
    }
    __syncthreads();
    const size_t pb = (size_t)(row0 >> 4) + blockIdx.x;
    for (int c = tid; c < NCOLS; c += 256)
        partials[pb*NCOLS + c] = probacc[0][c] + probacc[1][c] + probacc[2][c] + probacc[3][c];
}

// ---------------- fixup v2: 4 waves split K, LDS reduce, pipelined loads ----------------
__global__ __launch_bounds__(256) void fixup_kernel(
    const float* __restrict__ x, const float* __restrict__ W,
    const float* __restrict__ bias, const float* __restrict__ cb,
    float* __restrict__ qout, const int* __restrict__ counter, const int* __restrict__ list)
{
    __shared__ float red[4][NVARS];    // per-wave partial logits
    int cnt = *counter; if (cnt > LISTCAP) cnt = LISTCAP;
    const int tid = threadIdx.x, w = tid >> 6, lane = tid & 63;

    for (int e = blockIdx.x; e < cnt; e += gridDim.x) {
        const int ent = list[e];
        const int row = ent >> 1, g = ent & 1;
        const float* xr = x + (size_t)row*FSZ;

        float acc[5] = {0.f, 0.f, 0.f, 0.f, 0.f};
        // wave w covers k in [w*192, w*192+192), x via float4, 4-way unrolled body
        for (int k0 = w*192; k0 < w*192 + 192; k0 += 4) {
            const float4 xv = *(const float4*)(xr + k0);
            const float xs[4] = {xv.x, xv.y, xv.z, xv.w};
            #pragma unroll
            for (int kk = 0; kk < 4; ++kk) {
                const float* wrow = W + (size_t)(k0 + kk)*NCOLS + g*NVARS;
                #pragma unroll
                for (int j = 0; j < 5; ++j)
                    acc[j] = fmaf(xs[kk], wrow[lane + 64*j], acc[j]);
            }
        }
        __syncthreads();   // previous iteration's red reads done
        #pragma unroll
        for (int j = 0; j < 5; ++j) red[w][lane + 64*j] = acc[j];
        __syncthreads();

        // all waves redundantly reduce + argmax (uniform result)
        float v[5];
        #pragma unroll
        for (int j = 0; j < 5; ++j) {
            const int c = lane + 64*j;
            v[j] = red[0][c] + red[1][c] + red[2][c] + red[3][c] + bias[g*NVARS + c];
        }
        float m = v[0]; int idx = lane;
        #pragma unroll
        for (int j = 1; j < 5; ++j) if (v[j] > m) { m = v[j]; idx = lane + 64*j; }
        #pragma unroll
        for (int off = 32; off > 0; off >>= 1) {
            float om = __shfl_xor(m, off);
            int   oi = __shfl_xor(idx, off);
            if (om > m || (om == m && oi < idx)) { m = om; idx = oi; }
        }
        if (w == 0) {
            const float2* srcc = (const float2*)(cb + (size_t)(g*NVARS + idx)*VDIM);
            float2* dst = (float2*)(qout + (size_t)row*QDIM + (size_t)g*VDIM);
            dst[lane] = srcc[lane];
        }
    }
}

// ---------------- reduce partials -> avg ----------------
__global__ __launch_bounds__(64) void reduce_kernel(
    const float* __restrict__ partials, float* __restrict__ avg)
{
    const int c = blockIdx.x, lane = threadIdx.x;
    float s = 0.f;
    for (int p = lane; p < BTOT/RPB; p += 64) s += partials[(size_t)p*NCOLS + c];
    #pragma unroll
    for (int off = 32; off > 0; off >>= 1) s += __shfl_xor(s, off);
    if (lane == 0) avg[c] = s;
}

// ---------------- finalize: ppl + temp ----------------
__global__ __launch_bounds__(64) void finalize_kernel(
    const float* __restrict__ avg, float* __restrict__ out)
{
    const int lane = threadIdx.x;
    float pp[GROUPS];
    #pragma unroll
    for (int g = 0; g < GROUPS; ++g) {
        float s = 0.f;
        #pragma unroll
        for (int j = 0; j < 5; ++j) {
            float p = avg[g*NVARS + lane + 64*j] * (1.0f/(float)BTOT);
            s += p * logf(p + 1e-7f);
        }
        #pragma unroll
        for (int off = 32; off > 0; off >>= 1) s += __shfl_xor(s, off);
        pp[g] = expf(-s);
    }
    if (lane == 0) {
        float ppl = pp[0] + pp[1];
        out[(size_t)BTOT*QDIM]     = ((float)NCOLS - ppl) / (float)NCOLS;
        out[(size_t)BTOT*QDIM + 1] = 2.0f;
    }
}

// ---------------- launcher ----------------
extern "C" void kernel_launch(void* const* d_in, const int* in_sizes, int n_in,
                              void* d_out, int out_size, void* d_ws, size_t ws_size,
                              hipStream_t stream)
{
    const float* x  = (const float*)d_in[0];
    const float* W  = (const float*)d_in[1];
    const float* b  = (const float*)d_in[2];
    const float* cb = (const float*)d_in[3];
    float* out = (float*)d_out;

    char* ws = (char*)d_ws;
    int*   counter  = (int*)ws;
    float* avg      = (float*)(ws + 1024);
    int*   list     = (int*)(ws + 8192);
    float* partials = (float*)(ws + 532480);
    __bf16* wh      = (__bf16*)(ws + 5775360);
    __bf16* wl      = (__bf16*)(ws + 6758400);
    char* chunkbase = ws + 7741440;

    long long avail = (long long)ws_size - 7741440;
    long long rmax = avail / 5632;
    int R = (int)((rmax / 1024) * 1024);
    if (R < 1024) R = (int)((rmax / 128) * 128);
    if (R > BTOT) R = BTOT;
    if (R < 128) R = 128;

    hipMemsetAsync(counter, 0, 4, stream);
    wpre<<<5*KT, 128, 0, stream>>>(W, wh, wl);

    for (int row0 = 0; row0 < BTOT; row0 += R) {
        int Rc = BTOT - row0; if (Rc > R) Rc = R;
        const int nmb = Rc / 128;
        __bf16* xh = (__bf16*)chunkbase;
        __bf16* xl = xh + (size_t)nmb*KT*4096;
        float* logits = (float*)(xl + (size_t)nmb*KT*4096);

        xpre<<<nmb*KT, 128, 0, stream>>>(x, xh, xl, row0);
        const int nwg = nmb * 5;
        gemm_mfma<<<nwg, 256, 0, stream>>>(xh, xl, wh, wl, b, logits, nwg);
        rows_kernel<<<Rc/RPB, 256, 0, stream>>>(logits, cb, out, partials, counter, list, row0);
    }
    fixup_kernel<<<512, 256, 0, stream>>>(x, W, b, cb, out, counter, list);
    reduce_kernel<<<NCOLS, 64, 0, stream>>>(partials, avg);
    finalize_kernel<<<1, 64, 0, stream>>>(avg, out);
}